// Round 15
// baseline (138.154 us; speedup 1.0000x reference)
//
#include <hip/hip_runtime.h>
#include <hip/hip_bf16.h>
#include <stdint.h>

#define NB 2048
#define NR 10
#define ND 1024
#define NTGT (NB * (NR - 1))   /* 18432 targets */
#define INV_TEMP 20.0f

#define BM 256
#define BN 192
#define BK 64                  /* fp8: 64 B rows in LDS */
#define NKT (ND / BK)          /* 16 K-tiles */
#define TM_TILES (NB / BM)     /* 8 */
#define TN_TILES (NTGT / BN)   /* 96 */
#define KTILE_BYTES ((BM + BN) * BK)   /* 28 KB */

typedef __attribute__((ext_vector_type(4))) float floatx4;
typedef __attribute__((ext_vector_type(2))) long longx2;

#define BAR()    asm volatile("s_barrier" ::: "memory")
#define VMCNT0() asm volatile("s_waitcnt vmcnt(0)" ::: "memory")

__device__ __forceinline__ void async16(const void* g, void* l) {
  __builtin_amdgcn_global_load_lds(
      (const __attribute__((address_space(1))) unsigned int*)g,
      (__attribute__((address_space(3))) unsigned int*)l,
      16, 0, 0);
}

// ---------------------------------------------------------------------------
// Kernel 1 (fused prep): one block per b. Reads the 10 rows of b ONCE:
// computes 10 norms + 9 anchor-dots, writes normalized FP8 (e4m3) A/T rows,
// KL, pos_score. Also zeroes sumexp[b].
// ---------------------------------------------------------------------------
__global__ __launch_bounds__(256) void prep_kernel(
    const float* __restrict__ emb, const float* __restrict__ scores,
    unsigned char* __restrict__ A8, unsigned char* __restrict__ T8,
    float* __restrict__ pos_score, float* __restrict__ kl_out,
    float* __restrict__ sumexp) {
  int b = blockIdx.x;
  int tid = threadIdx.x;             // float4 index within a row (256*4 = 1024)
  int wid = tid >> 6, lane = tid & 63;
  const float* base = emb + (size_t)b * NR * ND;

  if (tid == 32) sumexp[b] = 0.0f;   // fused memset (lane off the hot path)

  float4 v[NR];
  float ss[NR], dt[NR - 1];
#pragma unroll
  for (int r = 0; r < NR; ++r) {
    v[r] = reinterpret_cast<const float4*>(base + (size_t)r * ND)[tid];
    ss[r] = v[r].x * v[r].x + v[r].y * v[r].y + v[r].z * v[r].z + v[r].w * v[r].w;
  }
#pragma unroll
  for (int t = 0; t < NR - 1; ++t)
    dt[t] = v[0].x * v[t + 1].x + v[0].y * v[t + 1].y + v[0].z * v[t + 1].z +
            v[0].w * v[t + 1].w;

#pragma unroll
  for (int off = 32; off; off >>= 1) {
#pragma unroll
    for (int r = 0; r < NR; ++r) ss[r] += __shfl_xor(ss[r], off, 64);
#pragma unroll
    for (int t = 0; t < NR - 1; ++t) dt[t] += __shfl_xor(dt[t], off, 64);
  }
  __shared__ float red[4][2 * NR - 1];
  if (lane == 0) {
#pragma unroll
    for (int r = 0; r < NR; ++r) red[wid][r] = ss[r];
#pragma unroll
    for (int t = 0; t < NR - 1; ++t) red[wid][NR + t] = dt[t];
  }
  __syncthreads();

  float inv[NR];
#pragma unroll
  for (int r = 0; r < NR; ++r) {
    float s = red[0][r] + red[1][r] + red[2][r] + red[3][r];
    inv[r] = 1.0f / fmaxf(sqrtf(s), 1e-12f);
  }

  // write normalized fp8 rows (4 bytes/thread/row)
#pragma unroll
  for (int r = 0; r < NR; ++r) {
    unsigned char* dst;
    if (r == 0)      dst = A8 + (size_t)b * ND;
    else if (r == 1) dst = T8 + (size_t)b * ND;
    else             dst = T8 + (size_t)(NB + b * 8 + (r - 2)) * ND;
    int p = 0;
    p = __builtin_amdgcn_cvt_pk_fp8_f32(v[r].x * inv[r], v[r].y * inv[r], p, false);
    p = __builtin_amdgcn_cvt_pk_fp8_f32(v[r].z * inv[r], v[r].w * inv[r], p, true);
    reinterpret_cast<int*>(dst)[tid] = p;
  }

  if (tid == 0) {
    float rs[NR - 1];
#pragma unroll
    for (int t = 0; t < NR - 1; ++t) {
      float d = red[0][NR + t] + red[1][NR + t] + red[2][NR + t] + red[3][NR + t];
      rs[t] = d * inv[0] * inv[t + 1];
    }
    float sc[NR - 1], ms = -1e30f;
#pragma unroll
    for (int k = 0; k < NR - 1; ++k) { sc[k] = scores[b * (NR - 1) + k]; ms = fmaxf(ms, sc[k]); }
    float se = 0.f;
#pragma unroll
    for (int k = 0; k < NR - 1; ++k) { sc[k] = expf(sc[k] - ms); se += sc[k]; }
    float mr = -1e30f;
#pragma unroll
    for (int k = 0; k < NR - 1; ++k) mr = fmaxf(mr, rs[k]);
    float sr = 0.f;
#pragma unroll
    for (int k = 0; k < NR - 1; ++k) sr += expf(rs[k] - mr);
    float lz = logf(sr) + mr;
    float kl = 0.f;
#pragma unroll
    for (int k = 0; k < NR - 1; ++k) {
      float ce = sc[k] / se;
      kl += ce * logf(ce) - ce * (rs[k] - lz);
    }
    kl_out[b] = kl / (float)(NR - 1);
    pos_score[b] = rs[0];
  }
}

// ---------------------------------------------------------------------------
// Kernel 2: 256x192x64 FP8 (e4m3) GEMM + sum-exp epilogue, 1 block/CU.
// Round-11 schedule (triple buffer, counted vmcnt, ONE barrier/iter) with a
// bigger tile: 48 MFMA per wave-iter (was 32), LDS-reads/MFMA 0.229 (was
// 0.25), sync cost amortized over 1.5x more math. Grid 768 = 3 exact rounds.
// Staging by wave role: waves 0-3 stage A (4 loads each), waves 4-7 stage B
// (3 loads each); per-role counted vmcnt(4)/vmcnt(3). No launch-bounds reg
// cap: ~160 regs at 2 waves/SIMD (256 budget) -> no spill.
// ---------------------------------------------------------------------------

// A K-slice: 256 rows x 64 B = 16 KB; staged by waves 0..3 (4 loads each).
__device__ __forceinline__ void stage_A(const unsigned char* __restrict__ gtile,
                                        unsigned char* lds, int k0,
                                        int wid, int lane) {
  int li = wid * 64 + lane;            // 0..255
#pragma unroll
  for (int r = 0; r < 4; ++r) {
    int slot = r * 256 + li;           // 0..1023
    int lrow = slot >> 2;              // 0..255
    int u = (slot & 3) ^ ((lrow >> 1) & 3);
    async16(gtile + (size_t)lrow * ND + k0 + u * 16,
            lds + (r * 256 + wid * 64) * 16);   // wave-uniform base
  }
}

// B K-slice: 192 rows x 64 B = 12 KB; staged by waves 4..7 (3 loads each).
__device__ __forceinline__ void stage_B(const unsigned char* __restrict__ gtile,
                                        unsigned char* lds, int k0,
                                        int wid4, int lane) {
  int li = wid4 * 64 + lane;           // 0..255
#pragma unroll
  for (int r = 0; r < 3; ++r) {
    int slot = r * 256 + li;           // 0..767
    int lrow = slot >> 2;              // 0..191
    int u = (slot & 3) ^ ((lrow >> 1) & 3);
    async16(gtile + (size_t)lrow * ND + k0 + u * 16,
            lds + (r * 256 + wid4 * 64) * 16);  // wave-uniform base
  }
}

// Swizzled fragment-pair read: one b128; .x = kk0, .y = kk1 (k-permutation
// invariance: A and B use the same physical-k relabeling).
__device__ __forceinline__ longx2 frag8(const unsigned char* lds, int row, int lq) {
  int byte = row * 64 + ((lq * 16) ^ (((row >> 1) & 3) << 4));
  return *reinterpret_cast<const longx2*>(lds + byte);
}

__global__ __launch_bounds__(512) void gemm_lse_kernel(
    const unsigned char* __restrict__ A, const unsigned char* __restrict__ T,
    float* __restrict__ sumexp) {
  // 84 KiB: 3 x [As 16K][Bs 12K]
  __shared__ unsigned char smem[3 * KTILE_BYTES];

  int bid = blockIdx.x;             // 768 = 8 * 96
  int xcd = bid & 7;
  int j = bid >> 3;                 // 0..95
  int tn = xcd * 12 + (j >> 3);     // 12 B-panels per XCD
  int tm = j & 7;

  int tid = threadIdx.x;
  int wid = tid >> 6, lane = tid & 63;
  int wm = wid >> 2, wn = wid & 3;  // 2 x 4 waves; wave tile 128 x 48
  int lrow = lane & 15, lq = lane >> 4;
  bool isA = (wid < 4);

  const unsigned char* Ag = A + (size_t)tm * BM * ND;
  const unsigned char* Tg = T + (size_t)tn * BN * ND;

  floatx4 acc[8][3] = {};

  unsigned char* bufA[3], * bufB[3];
#pragma unroll
  for (int i = 0; i < 3; ++i) {
    bufA[i] = smem + i * KTILE_BYTES;
    bufB[i] = bufA[i] + BM * BK;
  }

  // Prologue: stage kt0 -> buf0, kt1 -> buf1; wait kt0 only.
  if (isA) {
    stage_A(Ag, bufA[0], 0, wid, lane);
    stage_A(Ag, bufA[1], BK, wid, lane);
    asm volatile("s_waitcnt vmcnt(4)" ::: "memory");
  } else {
    stage_B(Tg, bufB[0], 0, wid - 4, lane);
    stage_B(Tg, bufB[1], BK, wid - 4, lane);
    asm volatile("s_waitcnt vmcnt(3)" ::: "memory");
  }
  BAR();

  const unsigned char* Acur = bufA[0];  const unsigned char* Bcur = bufB[0];
  unsigned char* An = bufA[1];          unsigned char* Bn = bufB[1];
  unsigned char* Af = bufA[2];          unsigned char* Bf = bufB[2];

  for (int s = 0; s < NKT; ++s) {
    const int kn = ((s + 2) & (NKT - 1)) * BK;  // wrap: last 2 iters stage into
                                                // dead buffers (harmless)
    // stage kt s+2 (issued first for max slack; one full iter of cover)
    if (isA) stage_A(Ag, Af, kn, wid, lane);
    else     stage_B(Tg, Bf, kn, wid - 4, lane);

    longx2 aF[8], bF[3];
#pragma unroll
    for (int m = 0; m < 8; ++m)
      aF[m] = frag8(Acur, wm * 128 + m * 16 + lrow, lq);
#pragma unroll
    for (int n = 0; n < 3; ++n)
      bF[n] = frag8(Bcur, wn * 48 + n * 16 + lrow, lq);

    __builtin_amdgcn_s_setprio(1);
#pragma unroll
    for (int m = 0; m < 8; ++m)
#pragma unroll
      for (int n = 0; n < 3; ++n) {
        acc[m][n] = __builtin_amdgcn_mfma_f32_16x16x32_fp8_fp8(aF[m].x, bF[n].x, acc[m][n], 0, 0, 0);
        acc[m][n] = __builtin_amdgcn_mfma_f32_16x16x32_fp8_fp8(aF[m].y, bF[n].y, acc[m][n], 0, 0, 0);
      }
    __builtin_amdgcn_s_setprio(0);

    // kt s+1 fully landed: its loads were issued one full iter ago.
    if (isA) { asm volatile("s_waitcnt vmcnt(4)" ::: "memory"); }
    else     { asm volatile("s_waitcnt vmcnt(3)" ::: "memory"); }
    BAR();

    // rotate buffers
    unsigned char* ta = (unsigned char*)Acur;  unsigned char* tb = (unsigned char*)Bcur;
    Acur = An;  Bcur = Bn;
    An = Af;    Bn = Bf;
    Af = ta;    Bf = tb;
  }

  VMCNT0();  // drain wrapped final stages before LDS is released

  // Epilogue: per C-row partial sum of exp(sim*20) over this block's 192 cols.
#pragma unroll
  for (int m = 0; m < 8; ++m) {
#pragma unroll
    for (int j2 = 0; j2 < 4; ++j2) {
      float s = __expf(acc[m][0][j2] * INV_TEMP) + __expf(acc[m][1][j2] * INV_TEMP) +
                __expf(acc[m][2][j2] * INV_TEMP);
      s += __shfl_xor(s, 1, 64);
      s += __shfl_xor(s, 2, 64);
      s += __shfl_xor(s, 4, 64);
      s += __shfl_xor(s, 8, 64);
      if (lrow == 0) {
        int grow = tm * BM + wm * 128 + m * 16 + lq * 4 + j2;
        atomicAdd(&sumexp[grow], s);
      }
    }
  }
}

// ---------------------------------------------------------------------------
// Kernel 3: final scalar reduction.
// ---------------------------------------------------------------------------
__global__ __launch_bounds__(256) void finalize_kernel(
    const float* __restrict__ sumexp, const float* __restrict__ pos_score,
    const float* __restrict__ kl, float* __restrict__ out) {
  int tid = threadIdx.x;
  float kls = 0.f, ces = 0.f;
  for (int i = tid; i < NB; i += 256) {
    kls += kl[i];
    ces += logf(sumexp[i]) - pos_score[i] * INV_TEMP;
  }
#pragma unroll
  for (int off = 32; off; off >>= 1) {
    kls += __shfl_xor(kls, off, 64);
    ces += __shfl_xor(ces, off, 64);
  }
  __shared__ float sk[4], se4[4];
  int wid = tid >> 6, lane = tid & 63;
  if (lane == 0) { sk[wid] = kls; se4[wid] = ces; }
  __syncthreads();
  if (tid == 0) {
    float k4 = sk[0] + sk[1] + sk[2] + sk[3];
    float e4 = se4[0] + se4[1] + se4[2] + se4[3];
    out[0] = 0.5f * (k4 / (float)NB) + 1.0f * (e4 / (float)NB);
  }
}

extern "C" void kernel_launch(void* const* d_in, const int* in_sizes, int n_in,
                              void* d_out, int out_size, void* d_ws, size_t ws_size,
                              hipStream_t stream) {
  const float* emb = (const float*)d_in[0];
  const float* scores = (const float*)d_in[1];
  float* out = (float*)d_out;

  char* ws = (char*)d_ws;
  size_t offA = 0;
  size_t offT = offA + (size_t)NB * ND;          // fp8: 1 B/elem
  size_t offSum = offT + (size_t)NTGT * ND;
  size_t offPos = offSum + (size_t)NB * 4;
  size_t offKl = offPos + (size_t)NB * 4;

  unsigned char* A8 = (unsigned char*)(ws + offA);
  unsigned char* T8 = (unsigned char*)(ws + offT);
  float* sumexp = (float*)(ws + offSum);
  float* pos_score = (float*)(ws + offPos);
  float* kl = (float*)(ws + offKl);

  prep_kernel<<<NB, 256, 0, stream>>>(emb, scores, A8, T8, pos_score, kl, sumexp);
  gemm_lse_kernel<<<dim3(TM_TILES * TN_TILES), 512, 0, stream>>>(A8, T8, sumexp);
  finalize_kernel<<<1, 256, 0, stream>>>(sumexp, pos_score, kl, out);
}

// Round 16
// 88.750 us; speedup vs baseline: 1.5567x; 1.5567x over previous
//
#include <hip/hip_runtime.h>
#include <hip/hip_bf16.h>
#include <stdint.h>

#define NB 2048
#define NR 10
#define ND 1024
#define NTGT (NB * (NR - 1))   /* 18432 targets */
#define INV_TEMP 20.0f

#define BM 128
#define BN 192
#define BK 64                  /* fp8: 64 B rows in LDS */
#define NKT (ND / BK)          /* 16 K-tiles */
#define TM_TILES (NB / BM)     /* 16 */
#define TN_TILES (NTGT / BN)   /* 96 -> grid 1536 = 3 exact rounds of 512 */
#define KTILE_BYTES ((BM + BN) * BK)   /* 20 KB */

typedef __attribute__((ext_vector_type(4))) float floatx4;
typedef __attribute__((ext_vector_type(2))) long longx2;

#define BAR()    asm volatile("s_barrier" ::: "memory")
#define VMCNT0() asm volatile("s_waitcnt vmcnt(0)" ::: "memory")

__device__ __forceinline__ void async16(const void* g, void* l) {
  __builtin_amdgcn_global_load_lds(
      (const __attribute__((address_space(1))) unsigned int*)g,
      (__attribute__((address_space(3))) unsigned int*)l,
      16, 0, 0);
}

// ---------------------------------------------------------------------------
// Kernel 1 (fused prep): one block per b. Reads the 10 rows of b ONCE:
// computes 10 norms + 9 anchor-dots, writes normalized FP8 (e4m3) A/T rows,
// KL, pos_score. Also zeroes sumexp[b].
// ---------------------------------------------------------------------------
__global__ __launch_bounds__(256) void prep_kernel(
    const float* __restrict__ emb, const float* __restrict__ scores,
    unsigned char* __restrict__ A8, unsigned char* __restrict__ T8,
    float* __restrict__ pos_score, float* __restrict__ kl_out,
    float* __restrict__ sumexp) {
  int b = blockIdx.x;
  int tid = threadIdx.x;             // float4 index within a row (256*4 = 1024)
  int wid = tid >> 6, lane = tid & 63;
  const float* base = emb + (size_t)b * NR * ND;

  if (tid == 32) sumexp[b] = 0.0f;   // fused memset (lane off the hot path)

  float4 v[NR];
  float ss[NR], dt[NR - 1];
#pragma unroll
  for (int r = 0; r < NR; ++r) {
    v[r] = reinterpret_cast<const float4*>(base + (size_t)r * ND)[tid];
    ss[r] = v[r].x * v[r].x + v[r].y * v[r].y + v[r].z * v[r].z + v[r].w * v[r].w;
  }
#pragma unroll
  for (int t = 0; t < NR - 1; ++t)
    dt[t] = v[0].x * v[t + 1].x + v[0].y * v[t + 1].y + v[0].z * v[t + 1].z +
            v[0].w * v[t + 1].w;

#pragma unroll
  for (int off = 32; off; off >>= 1) {
#pragma unroll
    for (int r = 0; r < NR; ++r) ss[r] += __shfl_xor(ss[r], off, 64);
#pragma unroll
    for (int t = 0; t < NR - 1; ++t) dt[t] += __shfl_xor(dt[t], off, 64);
  }
  __shared__ float red[4][2 * NR - 1];
  if (lane == 0) {
#pragma unroll
    for (int r = 0; r < NR; ++r) red[wid][r] = ss[r];
#pragma unroll
    for (int t = 0; t < NR - 1; ++t) red[wid][NR + t] = dt[t];
  }
  __syncthreads();

  float inv[NR];
#pragma unroll
  for (int r = 0; r < NR; ++r) {
    float s = red[0][r] + red[1][r] + red[2][r] + red[3][r];
    inv[r] = 1.0f / fmaxf(sqrtf(s), 1e-12f);
  }

  // write normalized fp8 rows (4 bytes/thread/row)
#pragma unroll
  for (int r = 0; r < NR; ++r) {
    unsigned char* dst;
    if (r == 0)      dst = A8 + (size_t)b * ND;
    else if (r == 1) dst = T8 + (size_t)b * ND;
    else             dst = T8 + (size_t)(NB + b * 8 + (r - 2)) * ND;
    int p = 0;
    p = __builtin_amdgcn_cvt_pk_fp8_f32(v[r].x * inv[r], v[r].y * inv[r], p, false);
    p = __builtin_amdgcn_cvt_pk_fp8_f32(v[r].z * inv[r], v[r].w * inv[r], p, true);
    reinterpret_cast<int*>(dst)[tid] = p;
  }

  if (tid == 0) {
    float rs[NR - 1];
#pragma unroll
    for (int t = 0; t < NR - 1; ++t) {
      float d = red[0][NR + t] + red[1][NR + t] + red[2][NR + t] + red[3][NR + t];
      rs[t] = d * inv[0] * inv[t + 1];
    }
    float sc[NR - 1], ms = -1e30f;
#pragma unroll
    for (int k = 0; k < NR - 1; ++k) { sc[k] = scores[b * (NR - 1) + k]; ms = fmaxf(ms, sc[k]); }
    float se = 0.f;
#pragma unroll
    for (int k = 0; k < NR - 1; ++k) { sc[k] = expf(sc[k] - ms); se += sc[k]; }
    float mr = -1e30f;
#pragma unroll
    for (int k = 0; k < NR - 1; ++k) mr = fmaxf(mr, rs[k]);
    float sr = 0.f;
#pragma unroll
    for (int k = 0; k < NR - 1; ++k) sr += expf(rs[k] - mr);
    float lz = logf(sr) + mr;
    float kl = 0.f;
#pragma unroll
    for (int k = 0; k < NR - 1; ++k) {
      float ce = sc[k] / se;
      kl += ce * logf(ce) - ce * (rs[k] - lz);
    }
    kl_out[b] = kl / (float)(NR - 1);
    pos_score[b] = rs[0];
  }
}

// ---------------------------------------------------------------------------
// Kernel 2: 128x192x64 FP8 (e4m3) GEMM + sum-exp epilogue, 2 blocks/CU.
// Round-14 schedule (triple buffer 60 KiB, counted vmcnt, ONE barrier/iter)
// with grid 1536 = 3 EXACT rounds of 512 concurrent blocks (zero tail; round
// 14's 1152 grid wasted 25% in the last round). Per-wave staging: all waves
// 1 A-load; waves 0-3 two B-loads, waves 4-7 one -> waits vmcnt(3)/vmcnt(2).
// No launch-bounds reg cap (rounds 7/12 lesson); ~108 regs -> 4 waves/SIMD.
// ---------------------------------------------------------------------------

// Stage A K-slice: 128 rows x 64 B = 8 KB, 1 load/thread.
__device__ __forceinline__ void stage_A8(const unsigned char* __restrict__ gtile,
                                         unsigned char* lds, int k0, int tid) {
  int lrow = tid >> 2;                 // 0..127
  int u = (tid & 3) ^ ((lrow >> 1) & 3);
  async16(gtile + (size_t)lrow * ND + k0 + u * 16,
          lds + (tid & ~63) * 16);     // wave-uniform base, +lane*16B
}

// Stage B K-slice: 192 rows x 64 B = 12 KB, 1.5 loads/thread
// (row-block 128..191 staged by waves 0-3; wave-uniform split).
__device__ __forceinline__ void stage_B8(const unsigned char* __restrict__ gtile,
                                         unsigned char* lds, int k0, int tid) {
  int lrow0 = tid >> 2;                // 0..127
  int u0 = (tid & 3) ^ ((lrow0 >> 1) & 3);
  async16(gtile + (size_t)lrow0 * ND + k0 + u0 * 16,
          lds + (tid & ~63) * 16);
  if (tid < 256) {                     // waves 0-3
    int slot = 512 + tid;              // 512..767
    int lrow = slot >> 2;              // 128..191
    int u = (slot & 3) ^ ((lrow >> 1) & 3);
    async16(gtile + (size_t)lrow * ND + k0 + u * 16,
            lds + (512 + (tid & ~63)) * 16);
  }
}

// Swizzled fragment-pair read: one b128; .x = kk0, .y = kk1 (k-permutation
// invariance: A and B use the same physical-k relabeling).
__device__ __forceinline__ longx2 frag8(const unsigned char* lds, int row, int lq) {
  int byte = row * 64 + ((lq * 16) ^ (((row >> 1) & 3) << 4));
  return *reinterpret_cast<const longx2*>(lds + byte);
}

__global__ __launch_bounds__(512) void gemm_lse_kernel(
    const unsigned char* __restrict__ A, const unsigned char* __restrict__ T,
    float* __restrict__ sumexp) {
  // 60 KiB: 3 x [As 8K][Bs 12K]
  __shared__ unsigned char smem[3 * KTILE_BYTES];

  int bid = blockIdx.x;             // 1536 = 8 * 192
  int xcd = bid & 7;
  int j = bid >> 3;                 // 0..191
  int tn = xcd * 12 + (j >> 4);     // 12 B-panels per XCD
  int tm = j & 15;

  int tid = threadIdx.x;
  int wid = tid >> 6, lane = tid & 63;
  int wm = wid >> 2, wn = wid & 3;  // 2 x 4 waves; wave tile 64 x 48
  int lrow = lane & 15, lq = lane >> 4;

  const unsigned char* Ag = A + (size_t)tm * BM * ND;
  const unsigned char* Tg = T + (size_t)tn * BN * ND;

  floatx4 acc[4][3] = {};

  unsigned char* bufA[3], * bufB[3];
#pragma unroll
  for (int i = 0; i < 3; ++i) {
    bufA[i] = smem + i * KTILE_BYTES;
    bufB[i] = bufA[i] + BM * BK;
  }

  // Prologue: stage kt0 -> buf0, kt1 -> buf1; wait kt0 only (per-wave counted).
  stage_A8(Ag, bufA[0], 0, tid);
  stage_B8(Tg, bufB[0], 0, tid);
  stage_A8(Ag, bufA[1], BK, tid);
  stage_B8(Tg, bufB[1], BK, tid);
  if (wid < 4) { asm volatile("s_waitcnt vmcnt(3)" ::: "memory"); }
  else         { asm volatile("s_waitcnt vmcnt(2)" ::: "memory"); }
  BAR();

  const unsigned char* Acur = bufA[0];  const unsigned char* Bcur = bufB[0];
  unsigned char* An = bufA[1];          unsigned char* Bn = bufB[1];   // kt s+1
  unsigned char* Af = bufA[2];          unsigned char* Bf = bufB[2];   // kt s+2

  for (int s = 0; s < NKT; ++s) {
    const int kn = ((s + 2) & (NKT - 1)) * BK;  // wrap: last 2 iters stage into
                                                // dead buffers (harmless)
    // stage kt s+2 (issued first for max slack: one full iter of cover)
    stage_A8(Ag, Af, kn, tid);
    stage_B8(Tg, Bf, kn, tid);

    longx2 aF[4], bF[3];
#pragma unroll
    for (int m = 0; m < 4; ++m)
      aF[m] = frag8(Acur, wm * 64 + m * 16 + lrow, lq);
#pragma unroll
    for (int n = 0; n < 3; ++n)
      bF[n] = frag8(Bcur, wn * 48 + n * 16 + lrow, lq);

    __builtin_amdgcn_s_setprio(1);
#pragma unroll
    for (int m = 0; m < 4; ++m)
#pragma unroll
      for (int n = 0; n < 3; ++n) {
        acc[m][n] = __builtin_amdgcn_mfma_f32_16x16x32_fp8_fp8(aF[m].x, bF[n].x, acc[m][n], 0, 0, 0);
        acc[m][n] = __builtin_amdgcn_mfma_f32_16x16x32_fp8_fp8(aF[m].y, bF[n].y, acc[m][n], 0, 0, 0);
      }
    __builtin_amdgcn_s_setprio(0);

    // kt s+1 fully landed: its loads were issued one full iter ago.
    if (wid < 4) { asm volatile("s_waitcnt vmcnt(3)" ::: "memory"); }
    else         { asm volatile("s_waitcnt vmcnt(2)" ::: "memory"); }
    BAR();

    // rotate buffers
    unsigned char* ta = (unsigned char*)Acur;  unsigned char* tb = (unsigned char*)Bcur;
    Acur = An;  Bcur = Bn;
    An = Af;    Bn = Bf;
    Af = ta;    Bf = tb;
  }

  VMCNT0();  // drain wrapped final stages before LDS is released

  // Epilogue: per C-row partial sum of exp(sim*20) over this block's 192 cols.
#pragma unroll
  for (int m = 0; m < 4; ++m) {
#pragma unroll
    for (int j2 = 0; j2 < 4; ++j2) {
      float s = __expf(acc[m][0][j2] * INV_TEMP) + __expf(acc[m][1][j2] * INV_TEMP) +
                __expf(acc[m][2][j2] * INV_TEMP);
      s += __shfl_xor(s, 1, 64);
      s += __shfl_xor(s, 2, 64);
      s += __shfl_xor(s, 4, 64);
      s += __shfl_xor(s, 8, 64);
      if (lrow == 0) {
        int grow = tm * BM + wm * 64 + m * 16 + lq * 4 + j2;
        atomicAdd(&sumexp[grow], s);
      }
    }
  }
}

// ---------------------------------------------------------------------------
// Kernel 3: final scalar reduction.
// ---------------------------------------------------------------------------
__global__ __launch_bounds__(256) void finalize_kernel(
    const float* __restrict__ sumexp, const float* __restrict__ pos_score,
    const float* __restrict__ kl, float* __restrict__ out) {
  int tid = threadIdx.x;
  float kls = 0.f, ces = 0.f;
  for (int i = tid; i < NB; i += 256) {
    kls += kl[i];
    ces += logf(sumexp[i]) - pos_score[i] * INV_TEMP;
  }
#pragma unroll
  for (int off = 32; off; off >>= 1) {
    kls += __shfl_xor(kls, off, 64);
    ces += __shfl_xor(ces, off, 64);
  }
  __shared__ float sk[4], se4[4];
  int wid = tid >> 6, lane = tid & 63;
  if (lane == 0) { sk[wid] = kls; se4[wid] = ces; }
  __syncthreads();
  if (tid == 0) {
    float k4 = sk[0] + sk[1] + sk[2] + sk[3];
    float e4 = se4[0] + se4[1] + se4[2] + se4[3];
    out[0] = 0.5f * (k4 / (float)NB) + 1.0f * (e4 / (float)NB);
  }
}

extern "C" void kernel_launch(void* const* d_in, const int* in_sizes, int n_in,
                              void* d_out, int out_size, void* d_ws, size_t ws_size,
                              hipStream_t stream) {
  const float* emb = (const float*)d_in[0];
  const float* scores = (const float*)d_in[1];
  float* out = (float*)d_out;

  char* ws = (char*)d_ws;
  size_t offA = 0;
  size_t offT = offA + (size_t)NB * ND;          // fp8: 1 B/elem
  size_t offSum = offT + (size_t)NTGT * ND;
  size_t offPos = offSum + (size_t)NB * 4;
  size_t offKl = offPos + (size_t)NB * 4;

  unsigned char* A8 = (unsigned char*)(ws + offA);
  unsigned char* T8 = (unsigned char*)(ws + offT);
  float* sumexp = (float*)(ws + offSum);
  float* pos_score = (float*)(ws + offPos);
  float* kl = (float*)(ws + offKl);

  prep_kernel<<<NB, 256, 0, stream>>>(emb, scores, A8, T8, pos_score, kl, sumexp);
  gemm_lse_kernel<<<dim3(TM_TILES * TN_TILES), 512, 0, stream>>>(A8, T8, sumexp);
  finalize_kernel<<<1, 256, 0, stream>>>(sumexp, pos_score, kl, out);
}

// Round 17
// 87.075 us; speedup vs baseline: 1.5866x; 1.0192x over previous
//
#include <hip/hip_runtime.h>
#include <hip/hip_bf16.h>
#include <stdint.h>

#define NB 2048
#define NR 10
#define ND 1024
#define NTGT (NB * (NR - 1))   /* 18432 targets */
#define INV_TEMP 20.0f

#define BM 128
#define BN 256
#define BK 64                  /* fp8: 64 B rows in LDS */
#define NKT (ND / BK)          /* 16 K-tiles */
#define TM_TILES (NB / BM)     /* 16 */
#define TN_TILES (NTGT / BN)   /* 72 */

typedef __attribute__((ext_vector_type(4))) float floatx4;
typedef __attribute__((ext_vector_type(2))) long longx2;

#define BAR()    asm volatile("s_barrier" ::: "memory")
#define VMCNT0() asm volatile("s_waitcnt vmcnt(0)" ::: "memory")
#define VMCNT3() asm volatile("s_waitcnt vmcnt(3)" ::: "memory")

__device__ __forceinline__ void async16(const void* g, void* l) {
  __builtin_amdgcn_global_load_lds(
      (const __attribute__((address_space(1))) unsigned int*)g,
      (__attribute__((address_space(3))) unsigned int*)l,
      16, 0, 0);
}

// ---------------------------------------------------------------------------
// Kernel 1 (fused prep): one block per b. Reads the 10 rows of b ONCE:
// computes 10 norms + 9 anchor-dots, writes normalized FP8 (e4m3) A/T rows,
// KL, pos_score. Also zeroes sumexp[b].
// ---------------------------------------------------------------------------
__global__ __launch_bounds__(256) void prep_kernel(
    const float* __restrict__ emb, const float* __restrict__ scores,
    unsigned char* __restrict__ A8, unsigned char* __restrict__ T8,
    float* __restrict__ pos_score, float* __restrict__ kl_out,
    float* __restrict__ sumexp) {
  int b = blockIdx.x;
  int tid = threadIdx.x;             // float4 index within a row (256*4 = 1024)
  int wid = tid >> 6, lane = tid & 63;
  const float* base = emb + (size_t)b * NR * ND;

  if (tid == 32) sumexp[b] = 0.0f;   // fused memset (lane off the hot path)

  float4 v[NR];
  float ss[NR], dt[NR - 1];
#pragma unroll
  for (int r = 0; r < NR; ++r) {
    v[r] = reinterpret_cast<const float4*>(base + (size_t)r * ND)[tid];
    ss[r] = v[r].x * v[r].x + v[r].y * v[r].y + v[r].z * v[r].z + v[r].w * v[r].w;
  }
#pragma unroll
  for (int t = 0; t < NR - 1; ++t)
    dt[t] = v[0].x * v[t + 1].x + v[0].y * v[t + 1].y + v[0].z * v[t + 1].z +
            v[0].w * v[t + 1].w;

#pragma unroll
  for (int off = 32; off; off >>= 1) {
#pragma unroll
    for (int r = 0; r < NR; ++r) ss[r] += __shfl_xor(ss[r], off, 64);
#pragma unroll
    for (int t = 0; t < NR - 1; ++t) dt[t] += __shfl_xor(dt[t], off, 64);
  }
  __shared__ float red[4][2 * NR - 1];
  if (lane == 0) {
#pragma unroll
    for (int r = 0; r < NR; ++r) red[wid][r] = ss[r];
#pragma unroll
    for (int t = 0; t < NR - 1; ++t) red[wid][NR + t] = dt[t];
  }
  __syncthreads();

  float inv[NR];
#pragma unroll
  for (int r = 0; r < NR; ++r) {
    float s = red[0][r] + red[1][r] + red[2][r] + red[3][r];
    inv[r] = 1.0f / fmaxf(sqrtf(s), 1e-12f);
  }

  // write normalized fp8 rows (4 bytes/thread/row)
#pragma unroll
  for (int r = 0; r < NR; ++r) {
    unsigned char* dst;
    if (r == 0)      dst = A8 + (size_t)b * ND;
    else if (r == 1) dst = T8 + (size_t)b * ND;
    else             dst = T8 + (size_t)(NB + b * 8 + (r - 2)) * ND;
    int p = 0;
    p = __builtin_amdgcn_cvt_pk_fp8_f32(v[r].x * inv[r], v[r].y * inv[r], p, false);
    p = __builtin_amdgcn_cvt_pk_fp8_f32(v[r].z * inv[r], v[r].w * inv[r], p, true);
    reinterpret_cast<int*>(dst)[tid] = p;
  }

  if (tid == 0) {
    float rs[NR - 1];
#pragma unroll
    for (int t = 0; t < NR - 1; ++t) {
      float d = red[0][NR + t] + red[1][NR + t] + red[2][NR + t] + red[3][NR + t];
      rs[t] = d * inv[0] * inv[t + 1];
    }
    float sc[NR - 1], ms = -1e30f;
#pragma unroll
    for (int k = 0; k < NR - 1; ++k) { sc[k] = scores[b * (NR - 1) + k]; ms = fmaxf(ms, sc[k]); }
    float se = 0.f;
#pragma unroll
    for (int k = 0; k < NR - 1; ++k) { sc[k] = expf(sc[k] - ms); se += sc[k]; }
    float mr = -1e30f;
#pragma unroll
    for (int k = 0; k < NR - 1; ++k) mr = fmaxf(mr, rs[k]);
    float sr = 0.f;
#pragma unroll
    for (int k = 0; k < NR - 1; ++k) sr += expf(rs[k] - mr);
    float lz = logf(sr) + mr;
    float kl = 0.f;
#pragma unroll
    for (int k = 0; k < NR - 1; ++k) {
      float ce = sc[k] / se;
      kl += ce * logf(ce) - ce * (rs[k] - lz);
    }
    kl_out[b] = kl / (float)(NR - 1);
    pos_score[b] = rs[0];
  }
}

// ---------------------------------------------------------------------------
// Kernel 2: 128x256x64 FP8 (e4m3) GEMM + sum-exp epilogue, 2 blocks/CU.
// Round-14 geometry (best measured) with the sync point MOVED between the
// ds_reads and the MFMA block: {stage s+2; ds_read buf s; vmcnt(3); BAR;
// MFMA}. The reads complete during the vmcnt/barrier wait instead of
// stalling the MFMA (hides ~LDS latency + barrier skew each iter).
// Safety: RAW - buf s was confirmed by every wave's vmcnt before BAR(s-1),
// reads occur after it. WAR - staging of buf (s-1 mod 3) at iter s issues
// after BAR(s-1), which all waves reached only after their iter-(s-1)
// ds_reads retired. Same barrier/wait counts, repositioned only.
// ---------------------------------------------------------------------------

// Stage A K-slice: 128 rows x 64 B = 8 KB, 1 load/thread.
__device__ __forceinline__ void stage_A8(const unsigned char* __restrict__ gtile,
                                         unsigned char* lds, int k0, int tid) {
  int lrow = tid >> 2;                 // 0..127
  int u = (tid & 3) ^ ((lrow >> 1) & 3);
  const unsigned char* src = gtile + (size_t)lrow * ND + k0 + u * 16;
  unsigned char* dst = lds + (tid & ~63) * 16;  // wave-uniform base, +lane*16B
  async16(src, dst);
}

// Stage B K-slice: 256 rows x 64 B = 16 KB, 2 loads/thread.
__device__ __forceinline__ void stage_B8(const unsigned char* __restrict__ gtile,
                                         unsigned char* lds, int k0, int tid) {
#pragma unroll
  for (int r = 0; r < 2; ++r) {
    int slot = r * 512 + tid;          // 0..1023
    int lrow = slot >> 2;              // 0..255
    int u = (slot & 3) ^ ((lrow >> 1) & 3);
    const unsigned char* src = gtile + (size_t)lrow * ND + k0 + u * 16;
    unsigned char* dst = lds + (r * 512 + (tid & ~63)) * 16;
    async16(src, dst);
  }
}

// Swizzled fragment-pair read: one b128; .x = kk0, .y = kk1 (k-permutation
// invariance: A and B use the same physical-k relabeling).
__device__ __forceinline__ longx2 frag8(const unsigned char* lds, int row, int lq) {
  int byte = row * 64 + ((lq * 16) ^ (((row >> 1) & 3) << 4));
  return *reinterpret_cast<const longx2*>(lds + byte);
}

__global__ __launch_bounds__(512, 4) void gemm_lse_kernel(
    const unsigned char* __restrict__ A, const unsigned char* __restrict__ T,
    float* __restrict__ sumexp) {
  // 72 KiB: 3 x [As 8K][Bs 16K]
  __shared__ unsigned char smem[3 * (BM + BN) * BK];

  int bid = blockIdx.x;             // 1152 = 8 * 144
  int xcd = bid & 7;
  int j = bid >> 3;                 // 0..143
  int tn = xcd * 9 + (j >> 4);      // 9 B-panels per XCD
  int tm = j & 15;

  int tid = threadIdx.x;
  int wid = tid >> 6, lane = tid & 63;
  int wm = wid >> 2, wn = wid & 3;  // 2 x 4 waves; wave tile 64 x 64
  int lrow = lane & 15, lq = lane >> 4;

  const unsigned char* Ag = A + (size_t)tm * BM * ND;
  const unsigned char* Tg = T + (size_t)tn * BN * ND;

  floatx4 acc[4][4] = {};

  unsigned char* bufA0 = smem;
  unsigned char* bufB0 = smem + BM * BK;
  unsigned char* bufA1 = smem + (BM + BN) * BK;
  unsigned char* bufB1 = bufA1 + BM * BK;
  unsigned char* bufA2 = smem + 2 * (BM + BN) * BK;
  unsigned char* bufB2 = bufA2 + BM * BK;

  // Prologue: stage kt0 -> buf0, kt1 -> buf1; wait kt0 only.
  stage_A8(Ag, bufA0, 0, tid);
  stage_B8(Tg, bufB0, 0, tid);
  stage_A8(Ag, bufA1, BK, tid);
  stage_B8(Tg, bufB1, BK, tid);
  VMCNT3();
  BAR();

  const unsigned char* Acur = bufA0;  const unsigned char* Bcur = bufB0;
  unsigned char* An = bufA1;          unsigned char* Bn = bufB1;   // kt s+1
  unsigned char* Af = bufA2;          unsigned char* Bf = bufB2;   // kt s+2

  for (int s = 0; s < NKT; ++s) {
    const int kn = ((s + 2) & (NKT - 1)) * BK;  // wrap: last 2 iters stage into
                                                // dead buffers (harmless)
    // stage kt s+2 (issued first for max slack)
    stage_A8(Ag, Af, kn, tid);
    stage_B8(Tg, Bf, kn, tid);

    // ds_read buf s BEFORE the sync point: completes under vmcnt+barrier.
    longx2 aF[4], bF[4];
#pragma unroll
    for (int m = 0; m < 4; ++m)
      aF[m] = frag8(Acur, wm * 64 + m * 16 + lrow, lq);
#pragma unroll
    for (int n = 0; n < 4; ++n)
      bF[n] = frag8(Bcur, wn * 64 + n * 16 + lrow, lq);

    VMCNT3();   // confirm kt s+1 (issued one full iter ago) for next iter
    BAR();

    __builtin_amdgcn_s_setprio(1);
#pragma unroll
    for (int m = 0; m < 4; ++m)
#pragma unroll
      for (int n = 0; n < 4; ++n) {
        acc[m][n] = __builtin_amdgcn_mfma_f32_16x16x32_fp8_fp8(aF[m].x, bF[n].x, acc[m][n], 0, 0, 0);
        acc[m][n] = __builtin_amdgcn_mfma_f32_16x16x32_fp8_fp8(aF[m].y, bF[n].y, acc[m][n], 0, 0, 0);
      }
    __builtin_amdgcn_s_setprio(0);

    // rotate buffers
    unsigned char* ta = (unsigned char*)Acur;  unsigned char* tb = (unsigned char*)Bcur;
    Acur = An;  Bcur = Bn;
    An = Af;    Bn = Bf;
    Af = ta;    Bf = tb;
  }

  VMCNT0();  // drain wrapped final stages before LDS is released

  // Epilogue: per C-row partial sum of exp(sim*20) over this block's 256 cols.
#pragma unroll
  for (int m = 0; m < 4; ++m) {
#pragma unroll
    for (int j2 = 0; j2 < 4; ++j2) {
      float s = __expf(acc[m][0][j2] * INV_TEMP) + __expf(acc[m][1][j2] * INV_TEMP) +
                __expf(acc[m][2][j2] * INV_TEMP) + __expf(acc[m][3][j2] * INV_TEMP);
      s += __shfl_xor(s, 1, 64);
      s += __shfl_xor(s, 2, 64);
      s += __shfl_xor(s, 4, 64);
      s += __shfl_xor(s, 8, 64);
      if (lrow == 0) {
        int grow = tm * BM + wm * 64 + m * 16 + lq * 4 + j2;
        atomicAdd(&sumexp[grow], s);
      }
    }
  }
}

// ---------------------------------------------------------------------------
// Kernel 3: final scalar reduction.
// ---------------------------------------------------------------------------
__global__ __launch_bounds__(256) void finalize_kernel(
    const float* __restrict__ sumexp, const float* __restrict__ pos_score,
    const float* __restrict__ kl, float* __restrict__ out) {
  int tid = threadIdx.x;
  float kls = 0.f, ces = 0.f;
  for (int i = tid; i < NB; i += 256) {
    kls += kl[i];
    ces += logf(sumexp[i]) - pos_score[i] * INV_TEMP;
  }
#pragma unroll
  for (int off = 32; off; off >>= 1) {
    kls += __shfl_xor(kls, off, 64);
    ces += __shfl_xor(ces, off, 64);
  }
  __shared__ float sk[4], se4[4];
  int wid = tid >> 6, lane = tid & 63;
  if (lane == 0) { sk[wid] = kls; se4[wid] = ces; }
  __syncthreads();
  if (tid == 0) {
    float k4 = sk[0] + sk[1] + sk[2] + sk[3];
    float e4 = se4[0] + se4[1] + se4[2] + se4[3];
    out[0] = 0.5f * (k4 / (float)NB) + 1.0f * (e4 / (float)NB);
  }
}

extern "C" void kernel_launch(void* const* d_in, const int* in_sizes, int n_in,
                              void* d_out, int out_size, void* d_ws, size_t ws_size,
                              hipStream_t stream) {
  const float* emb = (const float*)d_in[0];
  const float* scores = (const float*)d_in[1];
  float* out = (float*)d_out;

  char* ws = (char*)d_ws;
  size_t offA = 0;
  size_t offT = offA + (size_t)NB * ND;          // fp8: 1 B/elem
  size_t offSum = offT + (size_t)NTGT * ND;
  size_t offPos = offSum + (size_t)NB * 4;
  size_t offKl = offPos + (size_t)NB * 4;

  unsigned char* A8 = (unsigned char*)(ws + offA);
  unsigned char* T8 = (unsigned char*)(ws + offT);
  float* sumexp = (float*)(ws + offSum);
  float* pos_score = (float*)(ws + offPos);
  float* kl = (float*)(ws + offKl);

  prep_kernel<<<NB, 256, 0, stream>>>(emb, scores, A8, T8, pos_score, kl, sumexp);
  gemm_lse_kernel<<<dim3(TM_TILES * TN_TILES), 512, 0, stream>>>(A8, T8, sumexp);
  finalize_kernel<<<1, 256, 0, stream>>>(sumexp, pos_score, kl, out);
}